// Round 10
// baseline (625.726 us; speedup 1.0000x reference)
//
#include <hip/hip_runtime.h>

#define NODE_DIM 256
#define HIDDEN 64
#define NUM_REL 10

#define FMA4(A, S, W) do { \
    (A).x = fmaf((S), (W).x, (A).x); \
    (A).y = fmaf((S), (W).y, (A).y); \
    (A).z = fmaf((S), (W).z, (A).z); \
    (A).w = fmaf((S), (W).w, (A).w); } while (0)

#define ELEM(V, I) ((I) == 0 ? (V).x : (I) == 1 ? (V).y : (I) == 2 ? (V).z : (V).w)

// ---- node kernel: round-5 version verbatim (~105 us; wave-uniform W rows ->
// s_load scalarization; thread-per-node). np/BLAS rounding order: acc=0,
// ascending-k fmaf chain, bias added AFTER as separate add, then relu.
//   h1 = relu((x@W1)+b1); h = (h1@W2)+b2 -> stored; A = h@W3[0:64] -> stored.
__global__ __launch_bounds__(256) void node_kernel(
    const float* __restrict__ x,
    const float* __restrict__ W1, const float* __restrict__ b1,
    const float* __restrict__ W2, const float* __restrict__ b2,
    const float* __restrict__ W3,
    float* __restrict__ Hout, float* __restrict__ Aout, int N)
{
    int n = blockIdx.x * 256 + threadIdx.x;
    if (n >= N) return;

    // ---- L1: h1 = relu((x@W1) + b1) ----
    float h1[64];
    #pragma unroll
    for (int j = 0; j < 64; ++j) h1[j] = 0.0f;

    const float4* xr = (const float4*)(x + (size_t)n * NODE_DIM);
    #pragma unroll 1
    for (int k4 = 0; k4 < NODE_DIM / 4; ++k4) {
        float4 xv = xr[k4];
        const float* w = W1 + (size_t)k4 * 4 * 64;
        #pragma unroll
        for (int j = 0; j < 64; ++j) h1[j] = fmaf(xv.x, w[j], h1[j]);
        #pragma unroll
        for (int j = 0; j < 64; ++j) h1[j] = fmaf(xv.y, w[64 + j], h1[j]);
        #pragma unroll
        for (int j = 0; j < 64; ++j) h1[j] = fmaf(xv.z, w[128 + j], h1[j]);
        #pragma unroll
        for (int j = 0; j < 64; ++j) h1[j] = fmaf(xv.w, w[192 + j], h1[j]);
    }
    #pragma unroll
    for (int j = 0; j < 64; ++j) h1[j] = fmaxf(h1[j] + b1[j], 0.0f);

    // ---- L2: h = (h1@W2) + b2 ----
    float h[64];
    #pragma unroll
    for (int c = 0; c < 4; ++c) {
        float acc[16];
        #pragma unroll
        for (int j = 0; j < 16; ++j) acc[j] = 0.0f;
        #pragma unroll
        for (int k = 0; k < 64; ++k) {
            const float* w = W2 + (size_t)k * 64 + c * 16;
            #pragma unroll
            for (int j = 0; j < 16; ++j) acc[j] = fmaf(h1[k], w[j], acc[j]);
        }
        #pragma unroll
        for (int j = 0; j < 16; ++j) h[c * 16 + j] = acc[j] + b2[c * 16 + j];
    }

    float4* hr = (float4*)(Hout + (size_t)n * 64);
    #pragma unroll
    for (int j4 = 0; j4 < 16; ++j4) {
        float4 v;
        v.x = h[4 * j4]; v.y = h[4 * j4 + 1];
        v.z = h[4 * j4 + 2]; v.w = h[4 * j4 + 3];
        hr[j4] = v;
    }

    // ---- L3 row-half partial: A = h @ W3[0:64], no bias ----
    float4* ar = (float4*)(Aout + (size_t)n * 64);
    #pragma unroll
    for (int c = 0; c < 4; ++c) {
        float acc[16];
        #pragma unroll
        for (int j = 0; j < 16; ++j) acc[j] = 0.0f;
        #pragma unroll
        for (int k = 0; k < 64; ++k) {
            const float* w = W3 + (size_t)k * 64 + c * 16;
            #pragma unroll
            for (int j = 0; j < 16; ++j) acc[j] = fmaf(h[k], w[j], acc[j]);
        }
        #pragma unroll
        for (int j4 = 0; j4 < 4; ++j4) {
            float4 v;
            v.x = acc[4 * j4]; v.y = acc[4 * j4 + 1];
            v.z = acc[4 * j4 + 2]; v.w = acc[4 * j4 + 3];
            ar[c * 4 + j4] = v;
        }
    }
}

// Per edge, LOW-VGPR structure (~58 live): process j-columns in two halves
// (0..31 then 32..63). Per half: 8 float4 accumulators seeded from A[row]
// (chain prefix), full k-chain over W3 rows 64..127 ascending with h[col]
// streamed one float4 ahead, +b3, relu, then logits accumulated over this
// half's j-range (ascending) into lg[10]. Chain order per output element is
// bit-identical to np's concat-gemm + relu + W4 gemm.
__global__ __launch_bounds__(256) void edge_kernel(
    const int* __restrict__ ei,
    const float* __restrict__ H, const float* __restrict__ A,
    const float* __restrict__ W3, const float* __restrict__ b3,
    const float* __restrict__ W4, const float* __restrict__ b4,
    float* __restrict__ out_type, float* __restrict__ out_probs, int E)
{
    int e = blockIdx.x * 256 + threadIdx.x;
    if (e >= E) return;

    int r = ei[e];
    int c = ei[E + e];

    const float4* Ar = (const float4*)(A + (size_t)r * 64);
    const float4* Hc = (const float4*)(H + (size_t)c * 64);
    const float* W3b = W3 + 64 * 64;

    float lg[NUM_REL];
    #pragma unroll
    for (int j = 0; j < NUM_REL; ++j) lg[j] = 0.0f;

    #pragma unroll
    for (int half = 0; half < 2; ++half) {      // fully unrolled: static indices
        // seed this half's 8 accumulators from the A chain prefix
        float4 acc[8];
        #pragma unroll
        for (int j = 0; j < 8; ++j) acc[j] = Ar[half * 8 + j];

        // k-chain: W3 rows 64..127 ascending, hc streamed one float4 ahead
        float4 hv = Hc[0];
        #pragma unroll 1
        for (int k4 = 0; k4 < 16; ++k4) {
            float4 hn = Hc[(k4 + 1) & 15];      // prefetch next (wrap harmless)
            #pragma unroll
            for (int i = 0; i < 4; ++i) {
                float s = ELEM(hv, i);
                const float* w = W3b + (size_t)(k4 * 4 + i) * 64 + half * 32;
                #pragma unroll
                for (int j = 0; j < 8; ++j) {
                    float4 wv = *(const float4*)(w + 4 * j);
                    FMA4(acc[j], s, wv);
                }
            }
            hv = hn;
        }

        // + b3, relu (this half's slice)
        #pragma unroll
        for (int j = 0; j < 8; ++j) {
            float4 bv = *(const float4*)(b3 + half * 32 + 4 * j);
            acc[j].x = fmaxf(acc[j].x + bv.x, 0.f);
            acc[j].y = fmaxf(acc[j].y + bv.y, 0.f);
            acc[j].z = fmaxf(acc[j].z + bv.z, 0.f);
            acc[j].w = fmaxf(acc[j].w + bv.w, 0.f);
        }

        // logits: continue lg chain over this half's j-range, ascending
        #pragma unroll
        for (int jq = 0; jq < 8; ++jq) {
            #pragma unroll
            for (int i = 0; i < 4; ++i) {
                float s = ELEM(acc[jq], i);
                const float* w = W4 + (size_t)(half * 32 + jq * 4 + i) * NUM_REL;
                #pragma unroll
                for (int j = 0; j < NUM_REL; ++j) lg[j] = fmaf(s, w[j], lg[j]);
            }
        }
    }

    #pragma unroll
    for (int j = 0; j < NUM_REL; ++j) lg[j] += b4[j];

    // argmax, first occurrence
    int best = 0;
    float bm = lg[0];
    #pragma unroll
    for (int j = 1; j < NUM_REL; ++j)
        if (lg[j] > bm) { bm = lg[j]; best = j; }

    // softmax fp32
    float p[NUM_REL];
    float sum = 0.0f;
    #pragma unroll
    for (int j = 0; j < NUM_REL; ++j) {
        p[j] = expf(lg[j] - bm);
        sum += p[j];
    }
    float inv = 1.0f / sum;

    out_type[e] = (float)best;
    float* op = out_probs + (size_t)e * NUM_REL;
    #pragma unroll
    for (int j = 0; j < NUM_REL; ++j) op[j] = p[j] * inv;
}

extern "C" void kernel_launch(void* const* d_in, const int* in_sizes, int n_in,
                              void* d_out, int out_size, void* d_ws, size_t ws_size,
                              hipStream_t stream)
{
    const float* x  = (const float*)d_in[0];
    const int*   ei = (const int*)d_in[1];
    const float* W1 = (const float*)d_in[2];
    const float* b1 = (const float*)d_in[3];
    const float* W2 = (const float*)d_in[4];
    const float* b2 = (const float*)d_in[5];
    const float* W3 = (const float*)d_in[6];
    const float* b3 = (const float*)d_in[7];
    const float* W4 = (const float*)d_in[8];
    const float* b4 = (const float*)d_in[9];

    int N = in_sizes[0] / NODE_DIM;   // 100000
    int E = in_sizes[1] / 2;          // 1600000

    // ws: H [N*64] f32 | A [N*64] f32   (51.2 MB total)
    float* H = (float*)d_ws;
    float* A = H + (size_t)N * 64;

    int nb = (N + 255) / 256;
    int eb = (E + 255) / 256;

    float* out_type  = (float*)d_out;
    float* out_probs = (float*)d_out + E;

    hipLaunchKernelGGL(node_kernel, dim3(nb), dim3(256), 0, stream,
                       x, W1, b1, W2, b2, W3, H, A, N);
    hipLaunchKernelGGL(edge_kernel, dim3(eb), dim3(256), 0, stream,
                       ei, H, A, W3, b3, W4, b4, out_type, out_probs, E);
}